// Round 8
// baseline (425.699 us; speedup 1.0000x reference)
//
#include <hip/hip_runtime.h>

// Problem constants (match reference)
#define N_NODES    1000000
#define N_EDGES    16000000
#define D          30
#define WINDOW     5
#define DEG_THRESH 10

// ---- binning params ----
#define P_PARTS    31                 // partitions of 32768 nodes
#define PART_BITS  15
#define PART_SIZE  32768
#define BIN_BLOCKS 256
#define BIN_THREADS 1024
#define BIN_ITERS  16                 // 256*1024*16 = 4,194,304 groups >= 4M
#define N_GROUPS   (N_EDGES / 4)      // 4,000,000 int4-groups
#define BM_WORDS   (N_NODES / 32)     // 31250 u32 = 125000 B

// deterministic per-(bucket, block) cells: no global allocator at all.
// per-cell records: mean 4228, sigma 64 -> 6400 = +34 sigma (never overflows;
// clamps below guard memory safety anyway).
#define NCELL      BIN_BLOCKS
#define SLOT_CAP   6400
#define BK_BYTES   ((size_t)P_PARTS * NCELL * SLOT_CAP * 2)   // 101,580,800
#define CCNT_OFF   BK_BYTES                                   // u32[P_PARTS*NCELL]
#define OUT_BYTES_NEEDED (BK_BYTES + (size_t)P_PARTS * NCELL * 4)

// dynamic LDS layout for bin_edges v7: bitmask + 31 cursors only
#define L_BM_BYTES   125000
#define L_TOTAL      (L_BM_BYTES + P_PARTS * 4)   // 125,124 B

// ---- phase 2 ----
#define SLICES     8
#define CELLS_PER_SLICE (NCELL / SLICES)       // 32
#define HIST_WORDS 16384              // 32768 nodes, u32 per 2 nodes (c0:u8|c1:u8)

// ---- ws layout (bytes) ----
#define WS_BM_OFF      0              // u32 bitmask (131072 B reserved)
#define WS_CUR_OFF     131072         // (kept reserved; unused by fast path now)
#define WS_PART_OFF    131328         // u32[248 * 16384] slice partials (15.5 MiB)
#define WS_NEEDED      (WS_PART_OFF + (size_t)P_PARTS * SLICES * HIST_WORDS * 4)

// ---------------------------------------------------------------------------
// Phase 0: pack atom_types into a 1-bit-per-node bitmask.
// ---------------------------------------------------------------------------
__global__ __launch_bounds__(256) void pack_types(
    const int* __restrict__ types,
    unsigned*  __restrict__ bm)
{
    const int g = blockIdx.x * 256 + threadIdx.x;
    const int v = (g < N_NODES) ? types[g] : 0;
    const unsigned long long m = __ballot(v);
    if ((threadIdx.x & 31) == 0 && g < N_NODES)
        bm[g >> 5] = (unsigned)(m >> (threadIdx.x & 32));
}

// ---------------------------------------------------------------------------
// Phase 1 v7: direct-to-cell stores, staging buffer DELETED.
// R7 analysis: at 78 us the LDS pipe dominated (~4 LDS lane-ops/record:
// bm read, cnt atomic, buf write, flush read ~= 60-100K cyc/CU + 28K
// conflict cyc), not barriers or HBM (both ~21%). The per-(bucket,block)
// cell cursor serializes positions itself, so records from a wave to one
// bucket land at consecutive offsets (~32B runs; cells fill densely -> L2
// merges lines). So: per record = 1 ds_add_rtn + 1 global_store_short.
// LDS ops/record 4 -> 2; barriers 25 -> 2; flush loop gone; LDS 122 KB.
// Load/bin loop shape preserved (int4 loads at top, independent record
// work) -- DO NOT hand-pipeline (round-3 regression).
// ---------------------------------------------------------------------------
__global__ __launch_bounds__(BIN_THREADS, 1) void bin_edges(
    const int*      __restrict__ edge_index,   // [2, N_EDGES] int32
    const unsigned* __restrict__ bm,           // type bitmask (global)
    unsigned short* __restrict__ buckets,      // [P_PARTS][NCELL][SLOT_CAP] in d_out
    unsigned*       __restrict__ cellcnt)      // [P_PARTS][NCELL] in d_out
{
    extern __shared__ char smem[];
    unsigned* bm_lds = (unsigned*)smem;                     // 125000 B
    unsigned* ccur   = (unsigned*)(smem + L_BM_BYTES);      // [31] block-local cursors

    const int tid = threadIdx.x;
    for (int i = tid; i < BM_WORDS; i += BIN_THREADS) bm_lds[i] = bm[i];
    if (tid < P_PARTS) ccur[tid] = 0u;
    __syncthreads();

    unsigned short* cellbase = buckets + (size_t)blockIdx.x * SLOT_CAP;

    for (int it = 0; it < BIN_ITERS; ++it) {
        const int g = (blockIdx.x * BIN_ITERS + it) * BIN_THREADS + tid;
        if (g < N_GROUPS) {
            const int e0 = g * 4;
            const int4 s4 = *reinterpret_cast<const int4*>(edge_index + e0);
            const int4 d4 = *reinterpret_cast<const int4*>(edge_index + N_EDGES + e0);
            const int ss[4] = {s4.x, s4.y, s4.z, s4.w};
            const int dd[4] = {d4.x, d4.y, d4.z, d4.w};
#pragma unroll
            for (int k = 0; k < 4; ++k) {
                const int s = ss[k], d = dd[k];
                const unsigned ts = (bm_lds[(unsigned)s >> 5] >> (s & 31)) & 1u;
                const unsigned td = (bm_lds[(unsigned)d >> 5] >> (d & 31)) & 1u;
                {   // record for endpoint s carries d's type
                    const int b = s >> PART_BITS;
                    const unsigned short rec =
                        (unsigned short)(((s & (PART_SIZE - 1)) << 1) | td);
                    const unsigned pos = atomicAdd(&ccur[b], 1u);
                    if (pos < SLOT_CAP)
                        cellbase[(size_t)b * NCELL * SLOT_CAP + pos] = rec;
                }
                {   // record for endpoint d carries s's type
                    const int b = d >> PART_BITS;
                    const unsigned short rec =
                        (unsigned short)(((d & (PART_SIZE - 1)) << 1) | ts);
                    const unsigned pos = atomicAdd(&ccur[b], 1u);
                    if (pos < SLOT_CAP)
                        cellbase[(size_t)b * NCELL * SLOT_CAP + pos] = rec;
                }
            }
        }
    }

    __syncthreads();
    if (tid < P_PARTS) {
        unsigned c = ccur[tid]; if (c > SLOT_CAP) c = SLOT_CAP;
        cellcnt[tid * NCELL + blockIdx.x] = c;
    }
}

// ---------------------------------------------------------------------------
// Phase 2 v2 (UNCHANGED from round 6 -- verified): counts preloaded once;
// 8 waves x 4 cells independently; uint4 record loads; uint4 init/copy-out.
// ---------------------------------------------------------------------------
__global__ __launch_bounds__(512) void hist_pass(
    const unsigned short* __restrict__ buckets,
    const unsigned*       __restrict__ cellcnt,
    unsigned*             __restrict__ partials)   // [P*SLICES][HIST_WORDS]
{
    __shared__ unsigned hist[HIST_WORDS];          // exactly 64 KiB
    __shared__ unsigned scnt[CELLS_PER_SLICE];
    const int p = blockIdx.x >> 3, s = blockIdx.x & 7;
    const int tid = threadIdx.x;

    uint4* h4 = reinterpret_cast<uint4*>(hist);
    for (int i = tid; i < HIST_WORDS / 4; i += 512)
        h4[i] = make_uint4(0u, 0u, 0u, 0u);
    if (tid < CELLS_PER_SLICE) {
        unsigned c = cellcnt[p * NCELL + s * CELLS_PER_SLICE + tid];
        scnt[tid] = (c > SLOT_CAP) ? SLOT_CAP : c;
    }
    __syncthreads();

    const int wv = tid >> 6, lane = tid & 63;
#pragma unroll
    for (int cc = 0; cc < CELLS_PER_SLICE / 8; ++cc) {   // 8 waves x 4 cells
        const int cl = wv * (CELLS_PER_SLICE / 8) + cc;  // local cell 0..31
        const unsigned count = scnt[cl];
        const unsigned short* bk =
            buckets + ((size_t)p * NCELL + s * CELLS_PER_SLICE + cl) * SLOT_CAP;
        const unsigned n8 = count >> 3;                  // uint4 = 8 records
        for (unsigned j = (unsigned)lane; j < n8; j += 64) {
            const uint4 q = *reinterpret_cast<const uint4*>(bk + j * 8u);
            const unsigned ww[4] = {q.x, q.y, q.z, q.w};
#pragma unroll
            for (int k = 0; k < 4; ++k) {
                const unsigned r0 = ww[k] & 0xFFFFu, r1 = ww[k] >> 16;
                unsigned local = r0 >> 1, t = r0 & 1u;
                atomicAdd(&hist[local >> 1], (1u << (8u * t)) << (16u * (local & 1u)));
                local = r1 >> 1; t = r1 & 1u;
                atomicAdd(&hist[local >> 1], (1u << (8u * t)) << (16u * (local & 1u)));
            }
        }
        for (unsigned i = (n8 << 3) + (unsigned)lane; i < count; i += 64) {
            const unsigned rec = bk[i];
            const unsigned local = rec >> 1, t = rec & 1u;
            atomicAdd(&hist[local >> 1], (1u << (8u * t)) << (16u * (local & 1u)));
        }
    }
    __syncthreads();
    uint4* op4 = reinterpret_cast<uint4*>(partials + (size_t)blockIdx.x * HIST_WORDS);
    for (int i = tid; i < HIST_WORDS / 4; i += 512) op4[i] = h4[i];
}

// ---------------------------------------------------------------------------
// Phase 3 (fused reduce + output) v4 (UNCHANGED): per-wave coalesced staging
// with float4 global transfers; padded LDS tile (ROW_PAD=33); register row,
// 5 dots vs W^T.
// ---------------------------------------------------------------------------
#define WT_STRIDE  36
#define OT_THREADS 256
#define OT_ROWPAD  33
__global__ __launch_bounds__(OT_THREADS) void out_pass(
    const float* __restrict__ x, const float* __restrict__ Wm,
    const unsigned* __restrict__ partials,
    const unsigned* __restrict__ bm,
    float* __restrict__ out)
{
    __shared__ float sWt[D * WT_STRIDE];                    // 4320 B
    __shared__ float stg[OT_THREADS / 64][64 * OT_ROWPAD];  // 4 x 8448 B
    const int tid = threadIdx.x;
    for (int i = tid; i < D * D; i += OT_THREADS) {
        const int k = i / D, c = i - k * D;   // Wm is [k][c] row-major
        sWt[c * WT_STRIDE + k] = Wm[i];
    }

    const int wv = tid >> 6, lane = tid & 63;
    const long blockBase = (long)blockIdx.x * OT_THREADS;   // first node of block
    const long waveBase  = blockBase + (long)wv * 64;       // first node of wave
    float* ws = stg[wv];
    const long f4base = (waveBase >> 1) * 15;               // wave's first float4
    const long f4lim  = (long)N_NODES * (D / 2) / 2;        // 7,500,000 float4 total

    // ---- stage-in: 480 contiguous float4, fully coalesced ----
    const float4* gx = reinterpret_cast<const float4*>(x);
#pragma unroll
    for (int it = 0; it < 8; ++it) {
        const int g = it * 64 + lane;               // 0..511, active < 480
        if (g < 480) {
            float4 v = make_float4(0.0f, 0.0f, 0.0f, 0.0f);
            if (f4base + g < f4lim) v = gx[f4base + g];
            const int pair = g / 15, within = g - pair * 15;
            const int r0 = pair * 2, f0 = within * 4;       // f0 in [0,56]
            const float vv[4] = {v.x, v.y, v.z, v.w};
#pragma unroll
            for (int e = 0; e < 4; ++e) {
                const int ff = f0 + e;                      // float idx in 2-row pair
                const int r  = r0 + (ff >= D);
                const int c  = ff - ((ff >= D) ? D : 0);
                ws[r * OT_ROWPAD + c] = vv[e];
            }
        }
    }
    __syncthreads();   // covers sWt + cross-lane stage-in

    // ---- criterion (window start) for this node ----
    const long n = blockBase + tid;
    int start = 0;
    if (n < N_NODES) {
        const unsigned Wd   = (unsigned)(n >> 1);   // partials word = 2 nodes
        const unsigned h    = (unsigned)n & 1u;
        const unsigned p    = Wd >> 14;
        const unsigned widx = Wd & 16383u;
        const unsigned* pp  = partials + (size_t)(p * SLICES) * HIST_WORDS + widx;
        unsigned sum = 0u;
#pragma unroll
        for (int s = 0; s < SLICES; ++s) sum += pp[(size_t)s * HIST_WORDS];
        const unsigned c0 = (sum >> (16u * h)) & 0xFFu;
        const unsigned c1 = (sum >> (16u * h + 8u)) & 0xFFu;
        const unsigned t  = (bm[n >> 5] >> ((unsigned)n & 31u)) & 1u;
        const unsigned cnt    = c0 + c1;
        const unsigned same_c = t ? c1 : c0;
        const unsigned diff_c = t ? c0 : c1;
        const int mix  = diff_c ? 0 : (same_c ? (int)t + 1 : 0);
        const int crit = (cnt > DEG_THRESH ? 3 : 0) + mix;
        start = crit * WINDOW;
    }

    // ---- own row -> registers (bank = (lane+k)%32 -> 2-way = free) ----
    float xr[D];
#pragma unroll
    for (int k = 0; k < D; ++k) xr[k] = ws[lane * OT_ROWPAD + k];

    // ---- 5 dots against W^T columns ----
    float acc[WINDOW];
    const float* wc0 = &sWt[start * WT_STRIDE];
#pragma unroll
    for (int j = 0; j < WINDOW; ++j) {
        const float* wc = wc0 + j * WT_STRIDE;
        float a = 0.0f;
#pragma unroll
        for (int k = 0; k < D; ++k) a += xr[k] * wc[k];
        acc[j] = a * 0.18257418583505536f;   // 1/sqrt(30)
    }
    __syncthreads();   // all row reads done before rows are overwritten

    // ---- assemble output row in LDS (own row only) ----
    float* wr = ws + lane * OT_ROWPAD;
#pragma unroll
    for (int k = 0; k < D; ++k) wr[k] = 0.0f;
#pragma unroll
    for (int j = 0; j < WINDOW; ++j) wr[start + j] = acc[j];
    __syncthreads();   // cross-lane before coalesced store

    // ---- stage-out: 480 contiguous float4, fully coalesced ----
    float4* gout = reinterpret_cast<float4*>(out);
#pragma unroll
    for (int it = 0; it < 8; ++it) {
        const int g = it * 64 + lane;
        if (g < 480 && f4base + g < f4lim) {
            const int pair = g / 15, within = g - pair * 15;
            const int r0 = pair * 2, f0 = within * 4;
            float vv[4];
#pragma unroll
            for (int e = 0; e < 4; ++e) {
                const int ff = f0 + e;
                const int r  = r0 + (ff >= D);
                const int c  = ff - ((ff >= D) ? D : 0);
                vv[e] = ws[r * OT_ROWPAD + c];
            }
            gout[f4base + g] = make_float4(vv[0], vv[1], vv[2], vv[3]);
        }
    }
}

// ===========================================================================
// Fallback (atomic path) if buffers are unexpectedly small.
// ===========================================================================
#define SAME_INC (1u << 12)
#define DIFF_INC (1u << 22)

__global__ __launch_bounds__(256) void edge_pass_atomic(
    const int* __restrict__ edge_index, const int* __restrict__ atom_types,
    unsigned* __restrict__ agg)
{
    const int t  = blockIdx.x * blockDim.x + threadIdx.x;
    const int e0 = t * 4;
    if (e0 >= N_EDGES) return;
    const int4 s4 = *reinterpret_cast<const int4*>(edge_index + e0);
    const int4 d4 = *reinterpret_cast<const int4*>(edge_index + N_EDGES + e0);
    const int ss[4] = {s4.x, s4.y, s4.z, s4.w};
    const int dd[4] = {d4.x, d4.y, d4.z, d4.w};
#pragma unroll
    for (int k = 0; k < 4; ++k) {
        const int s = ss[k], d = dd[k];
        const unsigned add = 1u + ((atom_types[s] == atom_types[d]) ? SAME_INC : DIFF_INC);
        atomicAdd(agg + s, add);
        atomicAdd(agg + d, add);
    }
}

__global__ __launch_bounds__(256) void out_pass_agg(
    const float* __restrict__ x, const float* __restrict__ Wm,
    const unsigned* __restrict__ agg, const int* __restrict__ atom_types,
    float* __restrict__ out)
{
    __shared__ float sx[64 * D];
    __shared__ float sW[D * D];
    __shared__ int   sstart[64];
    const int tid   = threadIdx.x;
    const long base = (long)blockIdx.x * 64;
    for (int i = tid; i < D * D; i += 256) sW[i] = Wm[i];
    const float* xb = x + base * D;
    for (int i = tid; i < 64 * D; i += 256) sx[i] = xb[i];
    if (tid < 64) {
        const long n = base + tid;
        const unsigned a = agg[n];
        const int cnt = a & 0xFFFu, sc = (a >> 12) & 0x3FFu, dc = a >> 22;
        const int mix  = dc ? 0 : (sc ? atom_types[n] + 1 : 0);
        sstart[tid] = ((cnt > DEG_THRESH ? 3 : 0) + mix) * WINDOW;
    }
    __syncthreads();
    const float scale = 0.18257418583505536f;
    float* ob = out + base * D;
    for (int i = tid; i < 64 * D; i += 256) {
        const int nd = i / D, c = i - nd * D;
        float v = 0.0f;
        if ((unsigned)(c - sstart[nd]) < WINDOW) {
            float acc = 0.0f;
#pragma unroll
            for (int k = 0; k < D; ++k) acc += sx[nd * D + k] * sW[k * D + c];
            v = acc * scale;
        }
        ob[i] = v;
    }
}

// ---------------------------------------------------------------------------
extern "C" void kernel_launch(void* const* d_in, const int* in_sizes, int n_in,
                              void* d_out, int out_size, void* d_ws, size_t ws_size,
                              hipStream_t stream)
{
    const float* x          = (const float*)d_in[0];
    const float* Wm         = (const float*)d_in[1];
    const int*   edge_index = (const int*)d_in[2];
    const int*   atom_types = (const int*)d_in[3];
    float* out = (float*)d_out;

    if (ws_size >= WS_NEEDED && (size_t)out_size * 4 >= OUT_BYTES_NEEDED) {
        char* ws = (char*)d_ws;
        unsigned*       bm       = (unsigned*)(ws + WS_BM_OFF);
        unsigned*       partials = (unsigned*)(ws + WS_PART_OFF);
        unsigned short* buckets  = (unsigned short*)d_out;   // scratch, overwritten
        unsigned*       cellcnt  = (unsigned*)((char*)d_out + CCNT_OFF);

        pack_types<<<(N_NODES + 255) / 256, 256, 0, stream>>>(atom_types, bm);
        bin_edges<<<BIN_BLOCKS, BIN_THREADS, L_TOTAL, stream>>>(edge_index, bm,
                                                                buckets, cellcnt);
        hist_pass<<<P_PARTS * SLICES, 512, 0, stream>>>(buckets, cellcnt, partials);
        out_pass<<<(N_NODES + OT_THREADS - 1) / OT_THREADS, OT_THREADS, 0, stream>>>(
            x, Wm, partials, bm, out);
    } else {
        unsigned* agg = (unsigned*)d_ws;
        hipMemsetAsync(agg, 0x00, N_NODES * sizeof(unsigned), stream);
        edge_pass_atomic<<<(N_EDGES / 4) / 256, 256, 0, stream>>>(edge_index, atom_types, agg);
        out_pass_agg<<<N_NODES / 64, 256, 0, stream>>>(x, Wm, agg, atom_types, out);
    }
}

// Round 9
// 364.179 us; speedup vs baseline: 1.1689x; 1.1689x over previous
//
#include <hip/hip_runtime.h>

// Problem constants (match reference)
#define N_NODES    1000000
#define N_EDGES    16000000
#define D          30
#define WINDOW     5
#define DEG_THRESH 10

// ---- binning params ----
#define P_PARTS    31                 // partitions of 32768 nodes
#define PART_BITS  15
#define PART_SIZE  32768
#define BUF_CAP    616                // staging entries/bucket (2-iter fill 528 +3.8sigma)
#define BIN_BLOCKS 256
#define BIN_THREADS 1024
#define BIN_ITERS  16                 // 256*1024*16 = 4,194,304 groups >= 4M
#define N_GROUPS   (N_EDGES / 4)      // 4,000,000 int4-groups
#define BM_WORDS   (N_NODES / 32)     // 31250 u32 = 125000 B

// deterministic per-(bucket, block) cells: no global allocator at all.
// per-cell records: mean 4228, sigma 64 -> 6400 = +34 sigma (never overflows;
// clamps below guard memory safety anyway).
#define NCELL      BIN_BLOCKS
#define SLOT_CAP   6400
#define BK_BYTES   ((size_t)P_PARTS * NCELL * SLOT_CAP * 2)   // 101,580,800
#define CCNT_OFF   BK_BYTES                                   // u32[P_PARTS*NCELL]
#define OUT_BYTES_NEEDED (BK_BYTES + (size_t)P_PARTS * NCELL * 4)

// dynamic LDS layout for bin_edges
#define L_BM_BYTES   125000
#define L_BUF_BYTES  (P_PARTS * BUF_CAP * 2)   // 38192
#define L_CNT_OFF    (L_BM_BYTES + L_BUF_BYTES)
#define L_TOTAL      (L_CNT_OFF + P_PARTS * 4 * 4)   // 163,688 B <= 163,840

// ---- phase 2 ----
#define SLICES     8
#define CELLS_PER_SLICE (NCELL / SLICES)       // 32
#define HIST_WORDS 16384              // 32768 nodes, u32 per 2 nodes (c0:u8|c1:u8)

// ---- ws layout (bytes) ----
#define WS_BM_OFF      0              // u32 bitmask (131072 B reserved)
#define WS_CUR_OFF     131072         // (kept reserved; unused by fast path now)
#define WS_PART_OFF    131328         // u32[248 * 16384] slice partials (15.5 MiB)
#define WS_NEEDED      (WS_PART_OFF + (size_t)P_PARTS * SLICES * HIST_WORDS * 4)

// ---------------------------------------------------------------------------
// Phase 0: pack atom_types into a 1-bit-per-node bitmask.
// ---------------------------------------------------------------------------
__global__ __launch_bounds__(256) void pack_types(
    const int* __restrict__ types,
    unsigned*  __restrict__ bm)
{
    const int g = blockIdx.x * 256 + threadIdx.x;
    const int v = (g < N_NODES) ? types[g] : 0;
    const unsigned long long m = __ballot(v);
    if ((threadIdx.x & 31) == 0 && g < N_NODES)
        bm[g >> 5] = (unsigned)(m >> (threadIdx.x & 32));
}

// ---------------------------------------------------------------------------
// Phase 1 v8 = R7 staged version (verified 78 us) + u32-packed flush ONLY.
// HARD-WON LESSONS (rounds 3, 8): the staged-buffer structure is load-
// bearing. Restructures that shrink per-record live state (hand prefetch,
// direct-to-cell stores) collapse the compiler schedule (VGPR 44/28->32/20,
// VALUBusy ~24%->9%) and DOUBLE the kernel time. Do not touch the load/bin
// body; flush-region edits (R5/R6/R7) have been safe.
// Flush change: copy staged records as packed u32 (halves LDS reads and
// global store instrs; head/tail scalar fixup for odd base/count).
// ---------------------------------------------------------------------------
__global__ __launch_bounds__(BIN_THREADS, 1) void bin_edges(
    const int*      __restrict__ edge_index,   // [2, N_EDGES] int32
    const unsigned* __restrict__ bm,           // type bitmask (global)
    unsigned short* __restrict__ buckets,      // [P_PARTS][NCELL][SLOT_CAP] in d_out
    unsigned*       __restrict__ cellcnt)      // [P_PARTS][NCELL] in d_out
{
    extern __shared__ char smem[];
    unsigned* bm_lds = (unsigned*)smem;                               // 125000 B
    unsigned short (*buf)[BUF_CAP] =
        (unsigned short(*)[BUF_CAP])(smem + L_BM_BYTES);              // 38192 B
    unsigned* cnt   = (unsigned*)(smem + L_CNT_OFF);                  // [31]
    unsigned* basev = cnt + P_PARTS;
    unsigned* ccnt  = basev + P_PARTS;
    unsigned* ccur  = ccnt + P_PARTS;                                 // block-local cell cursor

    const int tid = threadIdx.x;
    for (int i = tid; i < BM_WORDS; i += BIN_THREADS) bm_lds[i] = bm[i];
    if (tid < P_PARTS) { cnt[tid] = 0u; ccur[tid] = 0u; }
    __syncthreads();

    const size_t cellbase0 = (size_t)blockIdx.x * SLOT_CAP;   // + b*NCELL*SLOT_CAP

    for (int it = 0; it < BIN_ITERS; ++it) {
        const int g = (blockIdx.x * BIN_ITERS + it) * BIN_THREADS + tid;
        if (g < N_GROUPS) {
            const int e0 = g * 4;
            const int4 s4 = *reinterpret_cast<const int4*>(edge_index + e0);
            const int4 d4 = *reinterpret_cast<const int4*>(edge_index + N_EDGES + e0);
            const int ss[4] = {s4.x, s4.y, s4.z, s4.w};
            const int dd[4] = {d4.x, d4.y, d4.z, d4.w};
#pragma unroll
            for (int k = 0; k < 4; ++k) {
                const int s = ss[k], d = dd[k];
                const unsigned ts = (bm_lds[(unsigned)s >> 5] >> (s & 31)) & 1u;
                const unsigned td = (bm_lds[(unsigned)d >> 5] >> (d & 31)) & 1u;
                {   // record for endpoint s carries d's type
                    const int b = s >> PART_BITS;
                    const unsigned short rec =
                        (unsigned short)(((s & (PART_SIZE - 1)) << 1) | td);
                    const unsigned pos = atomicAdd(&cnt[b], 1u);
                    if (pos < BUF_CAP) buf[b][pos] = rec;
                    else {  // statistically ~never: direct spill into own cell
                        const unsigned gp = atomicAdd(&ccur[b], 1u);
                        if (gp < SLOT_CAP)
                            buckets[(size_t)b * NCELL * SLOT_CAP + cellbase0 + gp] = rec;
                    }
                }
                {   // record for endpoint d carries s's type
                    const int b = d >> PART_BITS;
                    const unsigned short rec =
                        (unsigned short)(((d & (PART_SIZE - 1)) << 1) | ts);
                    const unsigned pos = atomicAdd(&cnt[b], 1u);
                    if (pos < BUF_CAP) buf[b][pos] = rec;
                    else {
                        const unsigned gp = atomicAdd(&ccur[b], 1u);
                        if (gp < SLOT_CAP)
                            buckets[(size_t)b * NCELL * SLOT_CAP + cellbase0 + gp] = rec;
                    }
                }
            }
        }

        // ---- flush every 2 iterations ----
        if ((it & 1) == 1) {
            __syncthreads();   // all records of this period staged
            if (tid < P_PARTS) {   // LDS-only alloc: no global traffic
                unsigned c = cnt[tid]; if (c > BUF_CAP) c = BUF_CAP;
                unsigned bse = ccur[tid];
                if (bse > SLOT_CAP) bse = SLOT_CAP;
                if (bse + c > SLOT_CAP) c = SLOT_CAP - bse;   // memory-safety clamp
                ccur[tid] = bse + c;
                ccnt[tid] = c; basev[tid] = bse; cnt[tid] = 0u;
            }
            __syncthreads();
            // coalesced u32-packed flush: wave w copies buckets 2w, 2w+1
            const int w = tid >> 6, lane = tid & 63;
#pragma unroll
            for (int j = 0; j < 2; ++j) {
                const int b = w * 2 + j;
                if (b < P_PARTS) {
                    const unsigned c = ccnt[b];
                    if (c) {
                        const unsigned base = basev[b];
                        unsigned short* dstcell =
                            buckets + (size_t)b * NCELL * SLOT_CAP + cellbase0;
                        const unsigned head = base & 1u;   // odd only after ~never spill
                        if (head && lane == 0) dstcell[base] = buf[b][0];
                        const unsigned body = c - head;
                        const unsigned n2   = body >> 1;
                        unsigned* dst32 =
                            reinterpret_cast<unsigned*>(dstcell + base + head);
                        if (head == 0u) {   // aligned LDS u32 -> global u32
                            const unsigned* src32 =
                                reinterpret_cast<const unsigned*>(&buf[b][0]);
                            for (unsigned e = lane; e < n2; e += 64)
                                dst32[e] = src32[e];
                        } else {            // post-spill odd base: ultra-rare
                            for (unsigned e = lane; e < n2; e += 64) {
                                const unsigned lo = buf[b][1 + 2 * e];
                                const unsigned hi = buf[b][2 + 2 * e];
                                dst32[e] = lo | (hi << 16);
                            }
                        }
                        if ((body & 1u) && lane == 0)
                            dstcell[base + c - 1] = buf[b][c - 1];
                    }
                }
            }
            __syncthreads();   // buffers reusable
        }
    }

    if (tid < P_PARTS) {
        unsigned c = ccur[tid]; if (c > SLOT_CAP) c = SLOT_CAP;
        cellcnt[tid * NCELL + blockIdx.x] = c;
    }
}

// ---------------------------------------------------------------------------
// Phase 2 v2 (UNCHANGED from round 6 -- verified): counts preloaded once;
// 8 waves x 4 cells independently; uint4 record loads; uint4 init/copy-out.
// ---------------------------------------------------------------------------
__global__ __launch_bounds__(512) void hist_pass(
    const unsigned short* __restrict__ buckets,
    const unsigned*       __restrict__ cellcnt,
    unsigned*             __restrict__ partials)   // [P*SLICES][HIST_WORDS]
{
    __shared__ unsigned hist[HIST_WORDS];          // exactly 64 KiB
    __shared__ unsigned scnt[CELLS_PER_SLICE];
    const int p = blockIdx.x >> 3, s = blockIdx.x & 7;
    const int tid = threadIdx.x;

    uint4* h4 = reinterpret_cast<uint4*>(hist);
    for (int i = tid; i < HIST_WORDS / 4; i += 512)
        h4[i] = make_uint4(0u, 0u, 0u, 0u);
    if (tid < CELLS_PER_SLICE) {
        unsigned c = cellcnt[p * NCELL + s * CELLS_PER_SLICE + tid];
        scnt[tid] = (c > SLOT_CAP) ? SLOT_CAP : c;
    }
    __syncthreads();

    const int wv = tid >> 6, lane = tid & 63;
#pragma unroll
    for (int cc = 0; cc < CELLS_PER_SLICE / 8; ++cc) {   // 8 waves x 4 cells
        const int cl = wv * (CELLS_PER_SLICE / 8) + cc;  // local cell 0..31
        const unsigned count = scnt[cl];
        const unsigned short* bk =
            buckets + ((size_t)p * NCELL + s * CELLS_PER_SLICE + cl) * SLOT_CAP;
        const unsigned n8 = count >> 3;                  // uint4 = 8 records
        for (unsigned j = (unsigned)lane; j < n8; j += 64) {
            const uint4 q = *reinterpret_cast<const uint4*>(bk + j * 8u);
            const unsigned ww[4] = {q.x, q.y, q.z, q.w};
#pragma unroll
            for (int k = 0; k < 4; ++k) {
                const unsigned r0 = ww[k] & 0xFFFFu, r1 = ww[k] >> 16;
                unsigned local = r0 >> 1, t = r0 & 1u;
                atomicAdd(&hist[local >> 1], (1u << (8u * t)) << (16u * (local & 1u)));
                local = r1 >> 1; t = r1 & 1u;
                atomicAdd(&hist[local >> 1], (1u << (8u * t)) << (16u * (local & 1u)));
            }
        }
        for (unsigned i = (n8 << 3) + (unsigned)lane; i < count; i += 64) {
            const unsigned rec = bk[i];
            const unsigned local = rec >> 1, t = rec & 1u;
            atomicAdd(&hist[local >> 1], (1u << (8u * t)) << (16u * (local & 1u)));
        }
    }
    __syncthreads();
    uint4* op4 = reinterpret_cast<uint4*>(partials + (size_t)blockIdx.x * HIST_WORDS);
    for (int i = tid; i < HIST_WORDS / 4; i += 512) op4[i] = h4[i];
}

// ---------------------------------------------------------------------------
// Phase 3 (fused reduce + output) v4 (UNCHANGED): per-wave coalesced staging
// with float4 global transfers; padded LDS tile (ROW_PAD=33); register row,
// 5 dots vs W^T.
// ---------------------------------------------------------------------------
#define WT_STRIDE  36
#define OT_THREADS 256
#define OT_ROWPAD  33
__global__ __launch_bounds__(OT_THREADS) void out_pass(
    const float* __restrict__ x, const float* __restrict__ Wm,
    const unsigned* __restrict__ partials,
    const unsigned* __restrict__ bm,
    float* __restrict__ out)
{
    __shared__ float sWt[D * WT_STRIDE];                    // 4320 B
    __shared__ float stg[OT_THREADS / 64][64 * OT_ROWPAD];  // 4 x 8448 B
    const int tid = threadIdx.x;
    for (int i = tid; i < D * D; i += OT_THREADS) {
        const int k = i / D, c = i - k * D;   // Wm is [k][c] row-major
        sWt[c * WT_STRIDE + k] = Wm[i];
    }

    const int wv = tid >> 6, lane = tid & 63;
    const long blockBase = (long)blockIdx.x * OT_THREADS;   // first node of block
    const long waveBase  = blockBase + (long)wv * 64;       // first node of wave
    float* ws = stg[wv];
    const long f4base = (waveBase >> 1) * 15;               // wave's first float4
    const long f4lim  = (long)N_NODES * (D / 2) / 2;        // 7,500,000 float4 total

    // ---- stage-in: 480 contiguous float4, fully coalesced ----
    const float4* gx = reinterpret_cast<const float4*>(x);
#pragma unroll
    for (int it = 0; it < 8; ++it) {
        const int g = it * 64 + lane;               // 0..511, active < 480
        if (g < 480) {
            float4 v = make_float4(0.0f, 0.0f, 0.0f, 0.0f);
            if (f4base + g < f4lim) v = gx[f4base + g];
            const int pair = g / 15, within = g - pair * 15;
            const int r0 = pair * 2, f0 = within * 4;       // f0 in [0,56]
            const float vv[4] = {v.x, v.y, v.z, v.w};
#pragma unroll
            for (int e = 0; e < 4; ++e) {
                const int ff = f0 + e;                      // float idx in 2-row pair
                const int r  = r0 + (ff >= D);
                const int c  = ff - ((ff >= D) ? D : 0);
                ws[r * OT_ROWPAD + c] = vv[e];
            }
        }
    }
    __syncthreads();   // covers sWt + cross-lane stage-in

    // ---- criterion (window start) for this node ----
    const long n = blockBase + tid;
    int start = 0;
    if (n < N_NODES) {
        const unsigned Wd   = (unsigned)(n >> 1);   // partials word = 2 nodes
        const unsigned h    = (unsigned)n & 1u;
        const unsigned p    = Wd >> 14;
        const unsigned widx = Wd & 16383u;
        const unsigned* pp  = partials + (size_t)(p * SLICES) * HIST_WORDS + widx;
        unsigned sum = 0u;
#pragma unroll
        for (int s = 0; s < SLICES; ++s) sum += pp[(size_t)s * HIST_WORDS];
        const unsigned c0 = (sum >> (16u * h)) & 0xFFu;
        const unsigned c1 = (sum >> (16u * h + 8u)) & 0xFFu;
        const unsigned t  = (bm[n >> 5] >> ((unsigned)n & 31u)) & 1u;
        const unsigned cnt    = c0 + c1;
        const unsigned same_c = t ? c1 : c0;
        const unsigned diff_c = t ? c0 : c1;
        const int mix  = diff_c ? 0 : (same_c ? (int)t + 1 : 0);
        const int crit = (cnt > DEG_THRESH ? 3 : 0) + mix;
        start = crit * WINDOW;
    }

    // ---- own row -> registers (bank = (lane+k)%32 -> 2-way = free) ----
    float xr[D];
#pragma unroll
    for (int k = 0; k < D; ++k) xr[k] = ws[lane * OT_ROWPAD + k];

    // ---- 5 dots against W^T columns ----
    float acc[WINDOW];
    const float* wc0 = &sWt[start * WT_STRIDE];
#pragma unroll
    for (int j = 0; j < WINDOW; ++j) {
        const float* wc = wc0 + j * WT_STRIDE;
        float a = 0.0f;
#pragma unroll
        for (int k = 0; k < D; ++k) a += xr[k] * wc[k];
        acc[j] = a * 0.18257418583505536f;   // 1/sqrt(30)
    }
    __syncthreads();   // all row reads done before rows are overwritten

    // ---- assemble output row in LDS (own row only) ----
    float* wr = ws + lane * OT_ROWPAD;
#pragma unroll
    for (int k = 0; k < D; ++k) wr[k] = 0.0f;
#pragma unroll
    for (int j = 0; j < WINDOW; ++j) wr[start + j] = acc[j];
    __syncthreads();   // cross-lane before coalesced store

    // ---- stage-out: 480 contiguous float4, fully coalesced ----
    float4* gout = reinterpret_cast<float4*>(out);
#pragma unroll
    for (int it = 0; it < 8; ++it) {
        const int g = it * 64 + lane;
        if (g < 480 && f4base + g < f4lim) {
            const int pair = g / 15, within = g - pair * 15;
            const int r0 = pair * 2, f0 = within * 4;
            float vv[4];
#pragma unroll
            for (int e = 0; e < 4; ++e) {
                const int ff = f0 + e;
                const int r  = r0 + (ff >= D);
                const int c  = ff - ((ff >= D) ? D : 0);
                vv[e] = ws[r * OT_ROWPAD + c];
            }
            gout[f4base + g] = make_float4(vv[0], vv[1], vv[2], vv[3]);
        }
    }
}

// ===========================================================================
// Fallback (atomic path) if buffers are unexpectedly small.
// ===========================================================================
#define SAME_INC (1u << 12)
#define DIFF_INC (1u << 22)

__global__ __launch_bounds__(256) void edge_pass_atomic(
    const int* __restrict__ edge_index, const int* __restrict__ atom_types,
    unsigned* __restrict__ agg)
{
    const int t  = blockIdx.x * blockDim.x + threadIdx.x;
    const int e0 = t * 4;
    if (e0 >= N_EDGES) return;
    const int4 s4 = *reinterpret_cast<const int4*>(edge_index + e0);
    const int4 d4 = *reinterpret_cast<const int4*>(edge_index + N_EDGES + e0);
    const int ss[4] = {s4.x, s4.y, s4.z, s4.w};
    const int dd[4] = {d4.x, d4.y, d4.z, d4.w};
#pragma unroll
    for (int k = 0; k < 4; ++k) {
        const int s = ss[k], d = dd[k];
        const unsigned add = 1u + ((atom_types[s] == atom_types[d]) ? SAME_INC : DIFF_INC);
        atomicAdd(agg + s, add);
        atomicAdd(agg + d, add);
    }
}

__global__ __launch_bounds__(256) void out_pass_agg(
    const float* __restrict__ x, const float* __restrict__ Wm,
    const unsigned* __restrict__ agg, const int* __restrict__ atom_types,
    float* __restrict__ out)
{
    __shared__ float sx[64 * D];
    __shared__ float sW[D * D];
    __shared__ int   sstart[64];
    const int tid   = threadIdx.x;
    const long base = (long)blockIdx.x * 64;
    for (int i = tid; i < D * D; i += 256) sW[i] = Wm[i];
    const float* xb = x + base * D;
    for (int i = tid; i < 64 * D; i += 256) sx[i] = xb[i];
    if (tid < 64) {
        const long n = base + tid;
        const unsigned a = agg[n];
        const int cnt = a & 0xFFFu, sc = (a >> 12) & 0x3FFu, dc = a >> 22;
        const int mix  = dc ? 0 : (sc ? atom_types[n] + 1 : 0);
        sstart[tid] = ((cnt > DEG_THRESH ? 3 : 0) + mix) * WINDOW;
    }
    __syncthreads();
    const float scale = 0.18257418583505536f;
    float* ob = out + base * D;
    for (int i = tid; i < 64 * D; i += 256) {
        const int nd = i / D, c = i - nd * D;
        float v = 0.0f;
        if ((unsigned)(c - sstart[nd]) < WINDOW) {
            float acc = 0.0f;
#pragma unroll
            for (int k = 0; k < D; ++k) acc += sx[nd * D + k] * sW[k * D + c];
            v = acc * scale;
        }
        ob[i] = v;
    }
}

// ---------------------------------------------------------------------------
extern "C" void kernel_launch(void* const* d_in, const int* in_sizes, int n_in,
                              void* d_out, int out_size, void* d_ws, size_t ws_size,
                              hipStream_t stream)
{
    const float* x          = (const float*)d_in[0];
    const float* Wm         = (const float*)d_in[1];
    const int*   edge_index = (const int*)d_in[2];
    const int*   atom_types = (const int*)d_in[3];
    float* out = (float*)d_out;

    if (ws_size >= WS_NEEDED && (size_t)out_size * 4 >= OUT_BYTES_NEEDED) {
        char* ws = (char*)d_ws;
        unsigned*       bm       = (unsigned*)(ws + WS_BM_OFF);
        unsigned*       partials = (unsigned*)(ws + WS_PART_OFF);
        unsigned short* buckets  = (unsigned short*)d_out;   // scratch, overwritten
        unsigned*       cellcnt  = (unsigned*)((char*)d_out + CCNT_OFF);

        pack_types<<<(N_NODES + 255) / 256, 256, 0, stream>>>(atom_types, bm);
        bin_edges<<<BIN_BLOCKS, BIN_THREADS, L_TOTAL, stream>>>(edge_index, bm,
                                                                buckets, cellcnt);
        hist_pass<<<P_PARTS * SLICES, 512, 0, stream>>>(buckets, cellcnt, partials);
        out_pass<<<(N_NODES + OT_THREADS - 1) / OT_THREADS, OT_THREADS, 0, stream>>>(
            x, Wm, partials, bm, out);
    } else {
        unsigned* agg = (unsigned*)d_ws;
        hipMemsetAsync(agg, 0x00, N_NODES * sizeof(unsigned), stream);
        edge_pass_atomic<<<(N_EDGES / 4) / 256, 256, 0, stream>>>(edge_index, atom_types, agg);
        out_pass_agg<<<N_NODES / 64, 256, 0, stream>>>(x, Wm, agg, atom_types, out);
    }
}

// Round 10
// 360.039 us; speedup vs baseline: 1.1824x; 1.0115x over previous
//
#include <hip/hip_runtime.h>

// Problem constants (match reference)
#define N_NODES    1000000
#define N_EDGES    16000000
#define D          30
#define WINDOW     5
#define DEG_THRESH 10

// ---- binning params ----
#define P_PARTS    31                 // partitions of 32768 nodes
#define PART_BITS  15
#define PART_SIZE  32768
#define BUF_CAP    616                // staging entries/bucket (2-iter fill 528 +3.8sigma)
#define BIN_BLOCKS 256
#define BIN_THREADS 1024
#define BIN_ITERS  16                 // 256*1024*16 = 4,194,304 groups >= 4M
#define N_GROUPS   (N_EDGES / 4)      // 4,000,000 int4-groups
#define BM_WORDS   (N_NODES / 32)     // 31250 u32 = 125000 B

// deterministic per-(bucket, block) cells: no global allocator at all.
#define NCELL      BIN_BLOCKS
#define SLOT_CAP   6400
#define BK_BYTES   ((size_t)P_PARTS * NCELL * SLOT_CAP * 2)   // 101,580,800
#define CCNT_OFF   BK_BYTES                                   // u32[P_PARTS*NCELL]
#define OUT_BYTES_NEEDED (BK_BYTES + (size_t)P_PARTS * NCELL * 4)

// dynamic LDS layout for bin_edges
#define L_BM_BYTES   125000
#define L_BUF_BYTES  (P_PARTS * BUF_CAP * 2)   // 38192
#define L_CNT_OFF    (L_BM_BYTES + L_BUF_BYTES)
#define L_TOTAL      (L_CNT_OFF + P_PARTS * 4 * 4)   // 163,688 B <= 163,840

// ---- phase 2 ----
#define SLICES     8
#define CELLS_PER_SLICE (NCELL / SLICES)       // 32
#define HIST_WORDS 16384              // 32768 nodes, u32 per 2 nodes (c0:u8|c1:u8)

// ---- ws layout (bytes) ----
#define WS_BM_OFF      0              // u32 bitmask (131072 B reserved)
#define WS_CUR_OFF     131072         // (kept reserved; unused by fast path now)
#define WS_PART_OFF    131328         // u32[248 * 16384] slice partials (15.5 MiB)
#define WS_NEEDED      (WS_PART_OFF + (size_t)P_PARTS * SLICES * HIST_WORDS * 4)

// ---------------------------------------------------------------------------
// Phase 0: pack atom_types into a 1-bit-per-node bitmask.
// ---------------------------------------------------------------------------
__global__ __launch_bounds__(256) void pack_types(
    const int* __restrict__ types,
    unsigned*  __restrict__ bm)
{
    const int g = blockIdx.x * 256 + threadIdx.x;
    const int v = (g < N_NODES) ? types[g] : 0;
    const unsigned long long m = __ballot(v);
    if ((threadIdx.x & 31) == 0 && g < N_NODES)
        bm[g >> 5] = (unsigned)(m >> (threadIdx.x & 32));
}

// ---------------------------------------------------------------------------
// Phase 1 (EXACT round-7 version -- verified 78 us; CLOSED, do not touch).
// HARD-WON LESSONS (rounds 3, 8): the staged-buffer structure is load-
// bearing. Restructures that shrink per-record live state (hand prefetch,
// direct-to-cell stores) collapse the compiler schedule (VGPR 44/28->32/20,
// VALUBusy ~24%->9%) and DOUBLE the kernel time. R9's u32-packed flush was
// neutral. Flush-region edits safe; load/bin body is not.
// ---------------------------------------------------------------------------
__global__ __launch_bounds__(BIN_THREADS, 1) void bin_edges(
    const int*      __restrict__ edge_index,   // [2, N_EDGES] int32
    const unsigned* __restrict__ bm,           // type bitmask (global)
    unsigned short* __restrict__ buckets,      // [P_PARTS][NCELL][SLOT_CAP] in d_out
    unsigned*       __restrict__ cellcnt)      // [P_PARTS][NCELL] in d_out
{
    extern __shared__ char smem[];
    unsigned* bm_lds = (unsigned*)smem;                               // 125000 B
    unsigned short (*buf)[BUF_CAP] =
        (unsigned short(*)[BUF_CAP])(smem + L_BM_BYTES);              // 38192 B
    unsigned* cnt   = (unsigned*)(smem + L_CNT_OFF);                  // [31]
    unsigned* basev = cnt + P_PARTS;
    unsigned* ccnt  = basev + P_PARTS;
    unsigned* ccur  = ccnt + P_PARTS;                                 // block-local cell cursor

    const int tid = threadIdx.x;
    for (int i = tid; i < BM_WORDS; i += BIN_THREADS) bm_lds[i] = bm[i];
    if (tid < P_PARTS) { cnt[tid] = 0u; ccur[tid] = 0u; }
    __syncthreads();

    const size_t cellbase0 = (size_t)blockIdx.x * SLOT_CAP;   // + b*NCELL*SLOT_CAP

    for (int it = 0; it < BIN_ITERS; ++it) {
        const int g = (blockIdx.x * BIN_ITERS + it) * BIN_THREADS + tid;
        if (g < N_GROUPS) {
            const int e0 = g * 4;
            const int4 s4 = *reinterpret_cast<const int4*>(edge_index + e0);
            const int4 d4 = *reinterpret_cast<const int4*>(edge_index + N_EDGES + e0);
            const int ss[4] = {s4.x, s4.y, s4.z, s4.w};
            const int dd[4] = {d4.x, d4.y, d4.z, d4.w};
#pragma unroll
            for (int k = 0; k < 4; ++k) {
                const int s = ss[k], d = dd[k];
                const unsigned ts = (bm_lds[(unsigned)s >> 5] >> (s & 31)) & 1u;
                const unsigned td = (bm_lds[(unsigned)d >> 5] >> (d & 31)) & 1u;
                {   // record for endpoint s carries d's type
                    const int b = s >> PART_BITS;
                    const unsigned short rec =
                        (unsigned short)(((s & (PART_SIZE - 1)) << 1) | td);
                    const unsigned pos = atomicAdd(&cnt[b], 1u);
                    if (pos < BUF_CAP) buf[b][pos] = rec;
                    else {  // statistically ~never: direct spill into own cell
                        const unsigned gp = atomicAdd(&ccur[b], 1u);
                        if (gp < SLOT_CAP)
                            buckets[(size_t)b * NCELL * SLOT_CAP + cellbase0 + gp] = rec;
                    }
                }
                {   // record for endpoint d carries s's type
                    const int b = d >> PART_BITS;
                    const unsigned short rec =
                        (unsigned short)(((d & (PART_SIZE - 1)) << 1) | ts);
                    const unsigned pos = atomicAdd(&cnt[b], 1u);
                    if (pos < BUF_CAP) buf[b][pos] = rec;
                    else {
                        const unsigned gp = atomicAdd(&ccur[b], 1u);
                        if (gp < SLOT_CAP)
                            buckets[(size_t)b * NCELL * SLOT_CAP + cellbase0 + gp] = rec;
                    }
                }
            }
        }

        // ---- flush every 2 iterations ----
        if ((it & 1) == 1) {
            __syncthreads();   // all records of this period staged
            if (tid < P_PARTS) {   // LDS-only alloc: no global traffic
                unsigned c = cnt[tid]; if (c > BUF_CAP) c = BUF_CAP;
                unsigned bse = ccur[tid];
                if (bse > SLOT_CAP) bse = SLOT_CAP;
                if (bse + c > SLOT_CAP) c = SLOT_CAP - bse;   // memory-safety clamp
                ccur[tid] = bse + c;
                ccnt[tid] = c; basev[tid] = bse; cnt[tid] = 0u;
            }
            __syncthreads();
            // coalesced flush: wave w copies buckets 2w, 2w+1 into its own cells
            const int w = tid >> 6, lane = tid & 63;
#pragma unroll
            for (int j = 0; j < 2; ++j) {
                const int b = w * 2 + j;
                if (b < P_PARTS) {
                    const unsigned c = ccnt[b];
                    unsigned short* dst =
                        buckets + (size_t)b * NCELL * SLOT_CAP + cellbase0 + basev[b];
                    for (unsigned e = lane; e < c; e += 64) dst[e] = buf[b][e];
                }
            }
            __syncthreads();   // buffers reusable
        }
    }

    if (tid < P_PARTS) {
        unsigned c = ccur[tid]; if (c > SLOT_CAP) c = SLOT_CAP;
        cellcnt[tid * NCELL + blockIdx.x] = c;
    }
}

// ---------------------------------------------------------------------------
// Phase 2 v2 (UNCHANGED from round 6 -- verified): counts preloaded once;
// 8 waves x 4 cells independently; uint4 record loads; uint4 init/copy-out.
// ---------------------------------------------------------------------------
__global__ __launch_bounds__(512) void hist_pass(
    const unsigned short* __restrict__ buckets,
    const unsigned*       __restrict__ cellcnt,
    unsigned*             __restrict__ partials)   // [P*SLICES][HIST_WORDS]
{
    __shared__ unsigned hist[HIST_WORDS];          // exactly 64 KiB
    __shared__ unsigned scnt[CELLS_PER_SLICE];
    const int p = blockIdx.x >> 3, s = blockIdx.x & 7;
    const int tid = threadIdx.x;

    uint4* h4 = reinterpret_cast<uint4*>(hist);
    for (int i = tid; i < HIST_WORDS / 4; i += 512)
        h4[i] = make_uint4(0u, 0u, 0u, 0u);
    if (tid < CELLS_PER_SLICE) {
        unsigned c = cellcnt[p * NCELL + s * CELLS_PER_SLICE + tid];
        scnt[tid] = (c > SLOT_CAP) ? SLOT_CAP : c;
    }
    __syncthreads();

    const int wv = tid >> 6, lane = tid & 63;
#pragma unroll
    for (int cc = 0; cc < CELLS_PER_SLICE / 8; ++cc) {   // 8 waves x 4 cells
        const int cl = wv * (CELLS_PER_SLICE / 8) + cc;  // local cell 0..31
        const unsigned count = scnt[cl];
        const unsigned short* bk =
            buckets + ((size_t)p * NCELL + s * CELLS_PER_SLICE + cl) * SLOT_CAP;
        const unsigned n8 = count >> 3;                  // uint4 = 8 records
        for (unsigned j = (unsigned)lane; j < n8; j += 64) {
            const uint4 q = *reinterpret_cast<const uint4*>(bk + j * 8u);
            const unsigned ww[4] = {q.x, q.y, q.z, q.w};
#pragma unroll
            for (int k = 0; k < 4; ++k) {
                const unsigned r0 = ww[k] & 0xFFFFu, r1 = ww[k] >> 16;
                unsigned local = r0 >> 1, t = r0 & 1u;
                atomicAdd(&hist[local >> 1], (1u << (8u * t)) << (16u * (local & 1u)));
                local = r1 >> 1; t = r1 & 1u;
                atomicAdd(&hist[local >> 1], (1u << (8u * t)) << (16u * (local & 1u)));
            }
        }
        for (unsigned i = (n8 << 3) + (unsigned)lane; i < count; i += 64) {
            const unsigned rec = bk[i];
            const unsigned local = rec >> 1, t = rec & 1u;
            atomicAdd(&hist[local >> 1], (1u << (8u * t)) << (16u * (local & 1u)));
        }
    }
    __syncthreads();
    uint4* op4 = reinterpret_cast<uint4*>(partials + (size_t)blockIdx.x * HIST_WORDS);
    for (int i = tid; i < HIST_WORDS / 4; i += 512) op4[i] = h4[i];
}

// ---------------------------------------------------------------------------
// Phase 3 (fused reduce + output) v5: vectorized LDS + 2 barriers.
// Changes vs v4 (each kept within the proven macro-structure):
//  - ROWPAD 34 (even) -> row bases 8B-aligned -> ALL tile traffic is b64
//    (float2): 129 b32 ops/thread -> 62 b64 ops (stride-34 4-way aliasing
//    costs 1.58x/op per m136 but op count halves -> net ~0.79x, plus half
//    the issued instructions).
//  - register row assembly via cndmask (R1's verified pattern) replaces the
//    30-float zero pass in LDS.
//  - middle barrier DELETED: row read and row overwrite are own-row only --
//    no cross-lane hazard (v4's 3rd barrier was guarding nothing).
//  - criterion computed BEFORE the first barrier so its 8 partials loads
//    overlap the stage-in float4 loads.
// LDS/block: 4320 + 4*34816/4... = 39,136 B -> still 4 blocks/CU.
// ---------------------------------------------------------------------------
#define WT_STRIDE  36
#define OT_THREADS 256
#define OT_ROWPAD  34
__global__ __launch_bounds__(OT_THREADS) void out_pass(
    const float* __restrict__ x, const float* __restrict__ Wm,
    const unsigned* __restrict__ partials,
    const unsigned* __restrict__ bm,
    float* __restrict__ out)
{
    __shared__ float sWt[D * WT_STRIDE];                    // 4320 B
    __shared__ float stg[OT_THREADS / 64][64 * OT_ROWPAD];  // 4 x 8704 B
    const int tid = threadIdx.x;
    for (int i = tid; i < D * D; i += OT_THREADS) {
        const int k = i / D, c = i - k * D;   // Wm is [k][c] row-major
        sWt[c * WT_STRIDE + k] = Wm[i];
    }

    const int wv = tid >> 6, lane = tid & 63;
    const long blockBase = (long)blockIdx.x * OT_THREADS;   // first node of block
    const long waveBase  = blockBase + (long)wv * 64;       // first node of wave
    float* ws = stg[wv];
    const long f4base = (waveBase >> 1) * 15;               // wave's first float4
    const long f4lim  = (long)N_NODES * (D / 2) / 2;        // 7,500,000 float4 total

    // ---- criterion FIRST: partials/bm loads overlap stage-in loads ----
    const long n = blockBase + tid;
    int crit = 0;
    if (n < N_NODES) {
        const unsigned Wd   = (unsigned)(n >> 1);   // partials word = 2 nodes
        const unsigned h    = (unsigned)n & 1u;
        const unsigned p    = Wd >> 14;
        const unsigned widx = Wd & 16383u;
        const unsigned* pp  = partials + (size_t)(p * SLICES) * HIST_WORDS + widx;
        unsigned sum = 0u;
#pragma unroll
        for (int s = 0; s < SLICES; ++s) sum += pp[(size_t)s * HIST_WORDS];
        const unsigned c0 = (sum >> (16u * h)) & 0xFFu;
        const unsigned c1 = (sum >> (16u * h + 8u)) & 0xFFu;
        const unsigned t  = (bm[n >> 5] >> ((unsigned)n & 31u)) & 1u;
        const unsigned cnt    = c0 + c1;
        const unsigned same_c = t ? c1 : c0;
        const unsigned diff_c = t ? c0 : c1;
        const int mix  = diff_c ? 0 : (same_c ? (int)t + 1 : 0);
        crit = (cnt > DEG_THRESH ? 3 : 0) + mix;
    }
    const int start = crit * WINDOW;

    // ---- stage-in: 480 contiguous float4 -> 2x b64 LDS writes each ----
    const float4* gx = reinterpret_cast<const float4*>(x);
#pragma unroll
    for (int it = 0; it < 8; ++it) {
        const int g = it * 64 + lane;               // 0..511, active < 480
        if (g < 480) {
            float4 v = make_float4(0.0f, 0.0f, 0.0f, 0.0f);
            if (f4base + g < f4lim) v = gx[f4base + g];
            const int pair = g / 15, within = g - pair * 15;
            const int r0 = pair * 2, f0 = within * 4;       // f0 in {0,4,...,56}
            const int aw = (f0 >= D);                       // first float2
            const int bw = (f0 + 2 >= D);                   // second float2
            const int ra = r0 + aw, ca = f0 - (aw ? D : 0);
            const int rb = r0 + bw, cb = f0 + 2 - (bw ? D : 0);
            *reinterpret_cast<float2*>(&ws[ra * OT_ROWPAD + ca]) =
                make_float2(v.x, v.y);
            *reinterpret_cast<float2*>(&ws[rb * OT_ROWPAD + cb]) =
                make_float2(v.z, v.w);
        }
    }
    __syncthreads();   // covers sWt + cross-lane stage-in

    // ---- own row -> registers (15x b64) ----
    float xr[D];
    {
        const float* wr0 = &ws[lane * OT_ROWPAD];
#pragma unroll
        for (int i = 0; i < 15; ++i) {
            const float2 q = *reinterpret_cast<const float2*>(wr0 + 2 * i);
            xr[2 * i] = q.x; xr[2 * i + 1] = q.y;
        }
    }

    // ---- 5 dots against W^T columns ----
    float acc[WINDOW];
    const float* wc0 = &sWt[start * WT_STRIDE];
#pragma unroll
    for (int j = 0; j < WINDOW; ++j) {
        const float* wc = wc0 + j * WT_STRIDE;
        float a = 0.0f;
#pragma unroll
        for (int k = 0; k < D; ++k) a += xr[k] * wc[k];
        acc[j] = a * 0.18257418583505536f;   // 1/sqrt(30)
    }

    // ---- assemble output row in REGISTERS (cndmask), overwrite own row ----
    // No barrier needed: row read above and row write below are own-row only.
    float2 o[D / 2];
#pragma unroll
    for (int q = 0; q < D / WINDOW; ++q) {
        const bool m = (q == crit);
#pragma unroll
        for (int r = 0; r < WINDOW; ++r) {
            const float vv = m ? acc[r] : 0.0f;
            const int c = WINDOW * q + r;
            if (c & 1) o[c >> 1].y = vv; else o[c >> 1].x = vv;
        }
    }
    {
        float* wr0 = &ws[lane * OT_ROWPAD];
#pragma unroll
        for (int i = 0; i < 15; ++i)
            *reinterpret_cast<float2*>(wr0 + 2 * i) = o[i];
    }
    __syncthreads();   // cross-lane before coalesced store

    // ---- stage-out: 2x b64 LDS reads -> 480 contiguous float4 stores ----
    float4* gout = reinterpret_cast<float4*>(out);
#pragma unroll
    for (int it = 0; it < 8; ++it) {
        const int g = it * 64 + lane;
        if (g < 480 && f4base + g < f4lim) {
            const int pair = g / 15, within = g - pair * 15;
            const int r0 = pair * 2, f0 = within * 4;
            const int aw = (f0 >= D);
            const int bw = (f0 + 2 >= D);
            const int ra = r0 + aw, ca = f0 - (aw ? D : 0);
            const int rb = r0 + bw, cb = f0 + 2 - (bw ? D : 0);
            const float2 a =
                *reinterpret_cast<const float2*>(&ws[ra * OT_ROWPAD + ca]);
            const float2 b =
                *reinterpret_cast<const float2*>(&ws[rb * OT_ROWPAD + cb]);
            gout[f4base + g] = make_float4(a.x, a.y, b.x, b.y);
        }
    }
}

// ===========================================================================
// Fallback (atomic path) if buffers are unexpectedly small.
// ===========================================================================
#define SAME_INC (1u << 12)
#define DIFF_INC (1u << 22)

__global__ __launch_bounds__(256) void edge_pass_atomic(
    const int* __restrict__ edge_index, const int* __restrict__ atom_types,
    unsigned* __restrict__ agg)
{
    const int t  = blockIdx.x * blockDim.x + threadIdx.x;
    const int e0 = t * 4;
    if (e0 >= N_EDGES) return;
    const int4 s4 = *reinterpret_cast<const int4*>(edge_index + e0);
    const int4 d4 = *reinterpret_cast<const int4*>(edge_index + N_EDGES + e0);
    const int ss[4] = {s4.x, s4.y, s4.z, s4.w};
    const int dd[4] = {d4.x, d4.y, d4.z, d4.w};
#pragma unroll
    for (int k = 0; k < 4; ++k) {
        const int s = ss[k], d = dd[k];
        const unsigned add = 1u + ((atom_types[s] == atom_types[d]) ? SAME_INC : DIFF_INC);
        atomicAdd(agg + s, add);
        atomicAdd(agg + d, add);
    }
}

__global__ __launch_bounds__(256) void out_pass_agg(
    const float* __restrict__ x, const float* __restrict__ Wm,
    const unsigned* __restrict__ agg, const int* __restrict__ atom_types,
    float* __restrict__ out)
{
    __shared__ float sx[64 * D];
    __shared__ float sW[D * D];
    __shared__ int   sstart[64];
    const int tid   = threadIdx.x;
    const long base = (long)blockIdx.x * 64;
    for (int i = tid; i < D * D; i += 256) sW[i] = Wm[i];
    const float* xb = x + base * D;
    for (int i = tid; i < 64 * D; i += 256) sx[i] = xb[i];
    if (tid < 64) {
        const long n = base + tid;
        const unsigned a = agg[n];
        const int cnt = a & 0xFFFu, sc = (a >> 12) & 0x3FFu, dc = a >> 22;
        const int mix  = dc ? 0 : (sc ? atom_types[n] + 1 : 0);
        sstart[tid] = ((cnt > DEG_THRESH ? 3 : 0) + mix) * WINDOW;
    }
    __syncthreads();
    const float scale = 0.18257418583505536f;
    float* ob = out + base * D;
    for (int i = tid; i < 64 * D; i += 256) {
        const int nd = i / D, c = i - nd * D;
        float v = 0.0f;
        if ((unsigned)(c - sstart[nd]) < WINDOW) {
            float acc = 0.0f;
#pragma unroll
            for (int k = 0; k < D; ++k) acc += sx[nd * D + k] * sW[k * D + c];
            v = acc * scale;
        }
        ob[i] = v;
    }
}

// ---------------------------------------------------------------------------
extern "C" void kernel_launch(void* const* d_in, const int* in_sizes, int n_in,
                              void* d_out, int out_size, void* d_ws, size_t ws_size,
                              hipStream_t stream)
{
    const float* x          = (const float*)d_in[0];
    const float* Wm         = (const float*)d_in[1];
    const int*   edge_index = (const int*)d_in[2];
    const int*   atom_types = (const int*)d_in[3];
    float* out = (float*)d_out;

    if (ws_size >= WS_NEEDED && (size_t)out_size * 4 >= OUT_BYTES_NEEDED) {
        char* ws = (char*)d_ws;
        unsigned*       bm       = (unsigned*)(ws + WS_BM_OFF);
        unsigned*       partials = (unsigned*)(ws + WS_PART_OFF);
        unsigned short* buckets  = (unsigned short*)d_out;   // scratch, overwritten
        unsigned*       cellcnt  = (unsigned*)((char*)d_out + CCNT_OFF);

        pack_types<<<(N_NODES + 255) / 256, 256, 0, stream>>>(atom_types, bm);
        bin_edges<<<BIN_BLOCKS, BIN_THREADS, L_TOTAL, stream>>>(edge_index, bm,
                                                                buckets, cellcnt);
        hist_pass<<<P_PARTS * SLICES, 512, 0, stream>>>(buckets, cellcnt, partials);
        out_pass<<<(N_NODES + OT_THREADS - 1) / OT_THREADS, OT_THREADS, 0, stream>>>(
            x, Wm, partials, bm, out);
    } else {
        unsigned* agg = (unsigned*)d_ws;
        hipMemsetAsync(agg, 0x00, N_NODES * sizeof(unsigned), stream);
        edge_pass_atomic<<<(N_EDGES / 4) / 256, 256, 0, stream>>>(edge_index, atom_types, agg);
        out_pass_agg<<<N_NODES / 64, 256, 0, stream>>>(x, Wm, agg, atom_types, out);
    }
}

// Round 11
// 352.378 us; speedup vs baseline: 1.2081x; 1.0217x over previous
//
#include <hip/hip_runtime.h>

// Problem constants (match reference)
#define N_NODES    1000000
#define N_EDGES    16000000
#define D          30
#define WINDOW     5
#define DEG_THRESH 10

// ---- binning params ----
#define P_PARTS    31                 // partitions of 32768 nodes
#define PART_BITS  15
#define PART_SIZE  32768
#define BUF_CAP    616                // staging entries/bucket (2-iter fill 528 +3.8sigma)
#define BIN_BLOCKS 256
#define BIN_THREADS 1024
#define BIN_ITERS  16                 // 256*1024*16 = 4,194,304 groups >= 4M
#define N_GROUPS   (N_EDGES / 4)      // 4,000,000 int4-groups
#define BM_WORDS   (N_NODES / 32)     // 31250 u32 = 125000 B

// deterministic per-(bucket, block) cells: no global allocator at all.
#define NCELL      BIN_BLOCKS
#define SLOT_CAP   6400
#define BK_BYTES   ((size_t)P_PARTS * NCELL * SLOT_CAP * 2)   // 101,580,800
#define CCNT_OFF   BK_BYTES                                   // u32[P_PARTS*NCELL]
#define OUT_BYTES_NEEDED (BK_BYTES + (size_t)P_PARTS * NCELL * 4)

// dynamic LDS layout for bin_edges
#define L_BM_BYTES   125000
#define L_BUF_BYTES  (P_PARTS * BUF_CAP * 2)   // 38192
#define L_CNT_OFF    (L_BM_BYTES + L_BUF_BYTES)
#define L_TOTAL      (L_CNT_OFF + P_PARTS * 4 * 4)   // 163,688 B <= 163,840

// ---- phase 2 ----
#define SLICES     8
#define CELLS_PER_SLICE (NCELL / SLICES)       // 32
#define HIST_WORDS 16384              // 32768 nodes, u32 per 2 nodes (c0:u8|c1:u8)
#define HT_THREADS 1024               // 16 waves/CU (was 512 = 8 waves, 25% occ)

// ---- ws layout (bytes) ----
#define WS_BM_OFF      0              // u32 bitmask (131072 B reserved)
#define WS_CUR_OFF     131072         // (kept reserved; unused by fast path now)
#define WS_PART_OFF    131328         // u32[248 * 16384] slice partials (15.5 MiB)
#define WS_NEEDED      (WS_PART_OFF + (size_t)P_PARTS * SLICES * HIST_WORDS * 4)

// ---------------------------------------------------------------------------
// Phase 0: pack atom_types into a 1-bit-per-node bitmask.
// ---------------------------------------------------------------------------
__global__ __launch_bounds__(256) void pack_types(
    const int* __restrict__ types,
    unsigned*  __restrict__ bm)
{
    const int g = blockIdx.x * 256 + threadIdx.x;
    const int v = (g < N_NODES) ? types[g] : 0;
    const unsigned long long m = __ballot(v);
    if ((threadIdx.x & 31) == 0 && g < N_NODES)
        bm[g >> 5] = (unsigned)(m >> (threadIdx.x & 32));
}

// ---------------------------------------------------------------------------
// Phase 1 (EXACT round-7 version -- verified 76-78 us; CLOSED, do not touch).
// HARD-WON LESSONS (rounds 3, 8): the staged-buffer structure is load-
// bearing. Restructures that shrink per-record live state (hand prefetch,
// direct-to-cell stores) collapse the compiler schedule (VGPR 44/28->32/20,
// VALUBusy ~24%->9%) and DOUBLE the kernel time. R9's u32-packed flush was
// neutral. Flush-region edits safe; load/bin body is not.
// ---------------------------------------------------------------------------
__global__ __launch_bounds__(BIN_THREADS, 1) void bin_edges(
    const int*      __restrict__ edge_index,   // [2, N_EDGES] int32
    const unsigned* __restrict__ bm,           // type bitmask (global)
    unsigned short* __restrict__ buckets,      // [P_PARTS][NCELL][SLOT_CAP] in d_out
    unsigned*       __restrict__ cellcnt)      // [P_PARTS][NCELL] in d_out
{
    extern __shared__ char smem[];
    unsigned* bm_lds = (unsigned*)smem;                               // 125000 B
    unsigned short (*buf)[BUF_CAP] =
        (unsigned short(*)[BUF_CAP])(smem + L_BM_BYTES);              // 38192 B
    unsigned* cnt   = (unsigned*)(smem + L_CNT_OFF);                  // [31]
    unsigned* basev = cnt + P_PARTS;
    unsigned* ccnt  = basev + P_PARTS;
    unsigned* ccur  = ccnt + P_PARTS;                                 // block-local cell cursor

    const int tid = threadIdx.x;
    for (int i = tid; i < BM_WORDS; i += BIN_THREADS) bm_lds[i] = bm[i];
    if (tid < P_PARTS) { cnt[tid] = 0u; ccur[tid] = 0u; }
    __syncthreads();

    const size_t cellbase0 = (size_t)blockIdx.x * SLOT_CAP;   // + b*NCELL*SLOT_CAP

    for (int it = 0; it < BIN_ITERS; ++it) {
        const int g = (blockIdx.x * BIN_ITERS + it) * BIN_THREADS + tid;
        if (g < N_GROUPS) {
            const int e0 = g * 4;
            const int4 s4 = *reinterpret_cast<const int4*>(edge_index + e0);
            const int4 d4 = *reinterpret_cast<const int4*>(edge_index + N_EDGES + e0);
            const int ss[4] = {s4.x, s4.y, s4.z, s4.w};
            const int dd[4] = {d4.x, d4.y, d4.z, d4.w};
#pragma unroll
            for (int k = 0; k < 4; ++k) {
                const int s = ss[k], d = dd[k];
                const unsigned ts = (bm_lds[(unsigned)s >> 5] >> (s & 31)) & 1u;
                const unsigned td = (bm_lds[(unsigned)d >> 5] >> (d & 31)) & 1u;
                {   // record for endpoint s carries d's type
                    const int b = s >> PART_BITS;
                    const unsigned short rec =
                        (unsigned short)(((s & (PART_SIZE - 1)) << 1) | td);
                    const unsigned pos = atomicAdd(&cnt[b], 1u);
                    if (pos < BUF_CAP) buf[b][pos] = rec;
                    else {  // statistically ~never: direct spill into own cell
                        const unsigned gp = atomicAdd(&ccur[b], 1u);
                        if (gp < SLOT_CAP)
                            buckets[(size_t)b * NCELL * SLOT_CAP + cellbase0 + gp] = rec;
                    }
                }
                {   // record for endpoint d carries s's type
                    const int b = d >> PART_BITS;
                    const unsigned short rec =
                        (unsigned short)(((d & (PART_SIZE - 1)) << 1) | ts);
                    const unsigned pos = atomicAdd(&cnt[b], 1u);
                    if (pos < BUF_CAP) buf[b][pos] = rec;
                    else {
                        const unsigned gp = atomicAdd(&ccur[b], 1u);
                        if (gp < SLOT_CAP)
                            buckets[(size_t)b * NCELL * SLOT_CAP + cellbase0 + gp] = rec;
                    }
                }
            }
        }

        // ---- flush every 2 iterations ----
        if ((it & 1) == 1) {
            __syncthreads();   // all records of this period staged
            if (tid < P_PARTS) {   // LDS-only alloc: no global traffic
                unsigned c = cnt[tid]; if (c > BUF_CAP) c = BUF_CAP;
                unsigned bse = ccur[tid];
                if (bse > SLOT_CAP) bse = SLOT_CAP;
                if (bse + c > SLOT_CAP) c = SLOT_CAP - bse;   // memory-safety clamp
                ccur[tid] = bse + c;
                ccnt[tid] = c; basev[tid] = bse; cnt[tid] = 0u;
            }
            __syncthreads();
            // coalesced flush: wave w copies buckets 2w, 2w+1 into its own cells
            const int w = tid >> 6, lane = tid & 63;
#pragma unroll
            for (int j = 0; j < 2; ++j) {
                const int b = w * 2 + j;
                if (b < P_PARTS) {
                    const unsigned c = ccnt[b];
                    unsigned short* dst =
                        buckets + (size_t)b * NCELL * SLOT_CAP + cellbase0 + basev[b];
                    for (unsigned e = lane; e < c; e += 64) dst[e] = buf[b][e];
                }
            }
            __syncthreads();   // buffers reusable
        }
    }

    if (tid < P_PARTS) {
        unsigned c = ccur[tid]; if (c > SLOT_CAP) c = SLOT_CAP;
        cellcnt[tid * NCELL + blockIdx.x] = c;
    }
}

// ---------------------------------------------------------------------------
// Phase 2 v3: 1024 threads (16 waves/CU, was 8 at 512 -- grid is only 248
// blocks so blocks/CU can't exceed 1; doubling threads doubles in-flight
// record streams). 16 waves x 2 cells each; counts preloaded once; uint4
// record loads; uint4 init/copy-out. Histogram atomic pattern unchanged.
// ---------------------------------------------------------------------------
__global__ __launch_bounds__(HT_THREADS) void hist_pass(
    const unsigned short* __restrict__ buckets,
    const unsigned*       __restrict__ cellcnt,
    unsigned*             __restrict__ partials)   // [P*SLICES][HIST_WORDS]
{
    __shared__ unsigned hist[HIST_WORDS];          // exactly 64 KiB
    __shared__ unsigned scnt[CELLS_PER_SLICE];
    const int p = blockIdx.x >> 3, s = blockIdx.x & 7;
    const int tid = threadIdx.x;

    uint4* h4 = reinterpret_cast<uint4*>(hist);
    for (int i = tid; i < HIST_WORDS / 4; i += HT_THREADS)
        h4[i] = make_uint4(0u, 0u, 0u, 0u);
    if (tid < CELLS_PER_SLICE) {
        unsigned c = cellcnt[p * NCELL + s * CELLS_PER_SLICE + tid];
        scnt[tid] = (c > SLOT_CAP) ? SLOT_CAP : c;
    }
    __syncthreads();

    const int wv = tid >> 6, lane = tid & 63;      // wv in [0,16)
#pragma unroll
    for (int cc = 0; cc < CELLS_PER_SLICE / (HT_THREADS / 64); ++cc) {  // 2 cells/wave
        const int cl = wv * (CELLS_PER_SLICE / (HT_THREADS / 64)) + cc;
        const unsigned count = scnt[cl];
        const unsigned short* bk =
            buckets + ((size_t)p * NCELL + s * CELLS_PER_SLICE + cl) * SLOT_CAP;
        const unsigned n8 = count >> 3;                  // uint4 = 8 records
        for (unsigned j = (unsigned)lane; j < n8; j += 64) {
            const uint4 q = *reinterpret_cast<const uint4*>(bk + j * 8u);
            const unsigned ww[4] = {q.x, q.y, q.z, q.w};
#pragma unroll
            for (int k = 0; k < 4; ++k) {
                const unsigned r0 = ww[k] & 0xFFFFu, r1 = ww[k] >> 16;
                unsigned local = r0 >> 1, t = r0 & 1u;
                atomicAdd(&hist[local >> 1], (1u << (8u * t)) << (16u * (local & 1u)));
                local = r1 >> 1; t = r1 & 1u;
                atomicAdd(&hist[local >> 1], (1u << (8u * t)) << (16u * (local & 1u)));
            }
        }
        for (unsigned i = (n8 << 3) + (unsigned)lane; i < count; i += 64) {
            const unsigned rec = bk[i];
            const unsigned local = rec >> 1, t = rec & 1u;
            atomicAdd(&hist[local >> 1], (1u << (8u * t)) << (16u * (local & 1u)));
        }
    }
    __syncthreads();
    uint4* op4 = reinterpret_cast<uint4*>(partials + (size_t)blockIdx.x * HIST_WORDS);
    for (int i = tid; i < HIST_WORDS / 4; i += HT_THREADS) op4[i] = h4[i];
}

// ---------------------------------------------------------------------------
// Phase 3 (fused reduce + output) v5 (UNCHANGED from round 10 -- equal to v4
// with fewer ops/barriers; out_pass is global-request/latency-bound at this
// structure's limit: halving LDS ops + dropping a barrier was neutral).
// ---------------------------------------------------------------------------
#define WT_STRIDE  36
#define OT_THREADS 256
#define OT_ROWPAD  34
__global__ __launch_bounds__(OT_THREADS) void out_pass(
    const float* __restrict__ x, const float* __restrict__ Wm,
    const unsigned* __restrict__ partials,
    const unsigned* __restrict__ bm,
    float* __restrict__ out)
{
    __shared__ float sWt[D * WT_STRIDE];                    // 4320 B
    __shared__ float stg[OT_THREADS / 64][64 * OT_ROWPAD];  // 4 x 8704 B
    const int tid = threadIdx.x;
    for (int i = tid; i < D * D; i += OT_THREADS) {
        const int k = i / D, c = i - k * D;   // Wm is [k][c] row-major
        sWt[c * WT_STRIDE + k] = Wm[i];
    }

    const int wv = tid >> 6, lane = tid & 63;
    const long blockBase = (long)blockIdx.x * OT_THREADS;   // first node of block
    const long waveBase  = blockBase + (long)wv * 64;       // first node of wave
    float* ws = stg[wv];
    const long f4base = (waveBase >> 1) * 15;               // wave's first float4
    const long f4lim  = (long)N_NODES * (D / 2) / 2;        // 7,500,000 float4 total

    // ---- criterion FIRST: partials/bm loads overlap stage-in loads ----
    const long n = blockBase + tid;
    int crit = 0;
    if (n < N_NODES) {
        const unsigned Wd   = (unsigned)(n >> 1);   // partials word = 2 nodes
        const unsigned h    = (unsigned)n & 1u;
        const unsigned p    = Wd >> 14;
        const unsigned widx = Wd & 16383u;
        const unsigned* pp  = partials + (size_t)(p * SLICES) * HIST_WORDS + widx;
        unsigned sum = 0u;
#pragma unroll
        for (int s = 0; s < SLICES; ++s) sum += pp[(size_t)s * HIST_WORDS];
        const unsigned c0 = (sum >> (16u * h)) & 0xFFu;
        const unsigned c1 = (sum >> (16u * h + 8u)) & 0xFFu;
        const unsigned t  = (bm[n >> 5] >> ((unsigned)n & 31u)) & 1u;
        const unsigned cnt    = c0 + c1;
        const unsigned same_c = t ? c1 : c0;
        const unsigned diff_c = t ? c0 : c1;
        const int mix  = diff_c ? 0 : (same_c ? (int)t + 1 : 0);
        crit = (cnt > DEG_THRESH ? 3 : 0) + mix;
    }
    const int start = crit * WINDOW;

    // ---- stage-in: 480 contiguous float4 -> 2x b64 LDS writes each ----
    const float4* gx = reinterpret_cast<const float4*>(x);
#pragma unroll
    for (int it = 0; it < 8; ++it) {
        const int g = it * 64 + lane;               // 0..511, active < 480
        if (g < 480) {
            float4 v = make_float4(0.0f, 0.0f, 0.0f, 0.0f);
            if (f4base + g < f4lim) v = gx[f4base + g];
            const int pair = g / 15, within = g - pair * 15;
            const int r0 = pair * 2, f0 = within * 4;       // f0 in {0,4,...,56}
            const int aw = (f0 >= D);                       // first float2
            const int bw = (f0 + 2 >= D);                   // second float2
            const int ra = r0 + aw, ca = f0 - (aw ? D : 0);
            const int rb = r0 + bw, cb = f0 + 2 - (bw ? D : 0);
            *reinterpret_cast<float2*>(&ws[ra * OT_ROWPAD + ca]) =
                make_float2(v.x, v.y);
            *reinterpret_cast<float2*>(&ws[rb * OT_ROWPAD + cb]) =
                make_float2(v.z, v.w);
        }
    }
    __syncthreads();   // covers sWt + cross-lane stage-in

    // ---- own row -> registers (15x b64) ----
    float xr[D];
    {
        const float* wr0 = &ws[lane * OT_ROWPAD];
#pragma unroll
        for (int i = 0; i < 15; ++i) {
            const float2 q = *reinterpret_cast<const float2*>(wr0 + 2 * i);
            xr[2 * i] = q.x; xr[2 * i + 1] = q.y;
        }
    }

    // ---- 5 dots against W^T columns ----
    float acc[WINDOW];
    const float* wc0 = &sWt[start * WT_STRIDE];
#pragma unroll
    for (int j = 0; j < WINDOW; ++j) {
        const float* wc = wc0 + j * WT_STRIDE;
        float a = 0.0f;
#pragma unroll
        for (int k = 0; k < D; ++k) a += xr[k] * wc[k];
        acc[j] = a * 0.18257418583505536f;   // 1/sqrt(30)
    }

    // ---- assemble output row in REGISTERS (cndmask), overwrite own row ----
    // No barrier needed: row read above and row write below are own-row only.
    float2 o[D / 2];
#pragma unroll
    for (int q = 0; q < D / WINDOW; ++q) {
        const bool m = (q == crit);
#pragma unroll
        for (int r = 0; r < WINDOW; ++r) {
            const float vv = m ? acc[r] : 0.0f;
            const int c = WINDOW * q + r;
            if (c & 1) o[c >> 1].y = vv; else o[c >> 1].x = vv;
        }
    }
    {
        float* wr0 = &ws[lane * OT_ROWPAD];
#pragma unroll
        for (int i = 0; i < 15; ++i)
            *reinterpret_cast<float2*>(wr0 + 2 * i) = o[i];
    }
    __syncthreads();   // cross-lane before coalesced store

    // ---- stage-out: 2x b64 LDS reads -> 480 contiguous float4 stores ----
    float4* gout = reinterpret_cast<float4*>(out);
#pragma unroll
    for (int it = 0; it < 8; ++it) {
        const int g = it * 64 + lane;
        if (g < 480 && f4base + g < f4lim) {
            const int pair = g / 15, within = g - pair * 15;
            const int r0 = pair * 2, f0 = within * 4;
            const int aw = (f0 >= D);
            const int bw = (f0 + 2 >= D);
            const int ra = r0 + aw, ca = f0 - (aw ? D : 0);
            const int rb = r0 + bw, cb = f0 + 2 - (bw ? D : 0);
            const float2 a =
                *reinterpret_cast<const float2*>(&ws[ra * OT_ROWPAD + ca]);
            const float2 b =
                *reinterpret_cast<const float2*>(&ws[rb * OT_ROWPAD + cb]);
            gout[f4base + g] = make_float4(a.x, a.y, b.x, b.y);
        }
    }
}

// ===========================================================================
// Fallback (atomic path) if buffers are unexpectedly small.
// ===========================================================================
#define SAME_INC (1u << 12)
#define DIFF_INC (1u << 22)

__global__ __launch_bounds__(256) void edge_pass_atomic(
    const int* __restrict__ edge_index, const int* __restrict__ atom_types,
    unsigned* __restrict__ agg)
{
    const int t  = blockIdx.x * blockDim.x + threadIdx.x;
    const int e0 = t * 4;
    if (e0 >= N_EDGES) return;
    const int4 s4 = *reinterpret_cast<const int4*>(edge_index + e0);
    const int4 d4 = *reinterpret_cast<const int4*>(edge_index + N_EDGES + e0);
    const int ss[4] = {s4.x, s4.y, s4.z, s4.w};
    const int dd[4] = {d4.x, d4.y, d4.z, d4.w};
#pragma unroll
    for (int k = 0; k < 4; ++k) {
        const int s = ss[k], d = dd[k];
        const unsigned add = 1u + ((atom_types[s] == atom_types[d]) ? SAME_INC : DIFF_INC);
        atomicAdd(agg + s, add);
        atomicAdd(agg + d, add);
    }
}

__global__ __launch_bounds__(256) void out_pass_agg(
    const float* __restrict__ x, const float* __restrict__ Wm,
    const unsigned* __restrict__ agg, const int* __restrict__ atom_types,
    float* __restrict__ out)
{
    __shared__ float sx[64 * D];
    __shared__ float sW[D * D];
    __shared__ int   sstart[64];
    const int tid   = threadIdx.x;
    const long base = (long)blockIdx.x * 64;
    for (int i = tid; i < D * D; i += 256) sW[i] = Wm[i];
    const float* xb = x + base * D;
    for (int i = tid; i < 64 * D; i += 256) sx[i] = xb[i];
    if (tid < 64) {
        const long n = base + tid;
        const unsigned a = agg[n];
        const int cnt = a & 0xFFFu, sc = (a >> 12) & 0x3FFu, dc = a >> 22;
        const int mix  = dc ? 0 : (sc ? atom_types[n] + 1 : 0);
        sstart[tid] = ((cnt > DEG_THRESH ? 3 : 0) + mix) * WINDOW;
    }
    __syncthreads();
    const float scale = 0.18257418583505536f;
    float* ob = out + base * D;
    for (int i = tid; i < 64 * D; i += 256) {
        const int nd = i / D, c = i - nd * D;
        float v = 0.0f;
        if ((unsigned)(c - sstart[nd]) < WINDOW) {
            float acc = 0.0f;
#pragma unroll
            for (int k = 0; k < D; ++k) acc += sx[nd * D + k] * sW[k * D + c];
            v = acc * scale;
        }
        ob[i] = v;
    }
}

// ---------------------------------------------------------------------------
extern "C" void kernel_launch(void* const* d_in, const int* in_sizes, int n_in,
                              void* d_out, int out_size, void* d_ws, size_t ws_size,
                              hipStream_t stream)
{
    const float* x          = (const float*)d_in[0];
    const float* Wm         = (const float*)d_in[1];
    const int*   edge_index = (const int*)d_in[2];
    const int*   atom_types = (const int*)d_in[3];
    float* out = (float*)d_out;

    if (ws_size >= WS_NEEDED && (size_t)out_size * 4 >= OUT_BYTES_NEEDED) {
        char* ws = (char*)d_ws;
        unsigned*       bm       = (unsigned*)(ws + WS_BM_OFF);
        unsigned*       partials = (unsigned*)(ws + WS_PART_OFF);
        unsigned short* buckets  = (unsigned short*)d_out;   // scratch, overwritten
        unsigned*       cellcnt  = (unsigned*)((char*)d_out + CCNT_OFF);

        pack_types<<<(N_NODES + 255) / 256, 256, 0, stream>>>(atom_types, bm);
        bin_edges<<<BIN_BLOCKS, BIN_THREADS, L_TOTAL, stream>>>(edge_index, bm,
                                                                buckets, cellcnt);
        hist_pass<<<P_PARTS * SLICES, HT_THREADS, 0, stream>>>(buckets, cellcnt, partials);
        out_pass<<<(N_NODES + OT_THREADS - 1) / OT_THREADS, OT_THREADS, 0, stream>>>(
            x, Wm, partials, bm, out);
    } else {
        unsigned* agg = (unsigned*)d_ws;
        hipMemsetAsync(agg, 0x00, N_NODES * sizeof(unsigned), stream);
        edge_pass_atomic<<<(N_EDGES / 4) / 256, 256, 0, stream>>>(edge_index, atom_types, agg);
        out_pass_agg<<<N_NODES / 64, 256, 0, stream>>>(x, Wm, agg, atom_types, out);
    }
}